// Round 2
// baseline (16326.263 us; speedup 1.0000x reference)
//
#include <hip/hip_runtime.h>
#include <hip/hip_bf16.h>

#define NPTS  300000
#define KOFF  27
#define CIN   256
#define CMID  128
#define CS    32
#define COUT  8
#define BN_EPS 1e-5f
#define TILE_P 32

// ---------- bf16 helpers (manual, RNE) ----------
__device__ __forceinline__ float bf2f(unsigned short u){
  unsigned int x = ((unsigned int)u) << 16;
  return __uint_as_float(x);
}
__device__ __forceinline__ unsigned short f2bf(float f){
  unsigned int x = __float_as_uint(f);
  unsigned int r = (x + 0x7fffu + ((x >> 16) & 1u)) >> 16;
  return (unsigned short)r;
}

// ---------- mask dtype detection ----------
// int32 storage: ~100% of first words are 0/1. f32 storage: ~50% (the zeros).
// packed bool bytes: ~12.5%. Writes flag: 0=int32, 1=bytes, 2=f32.
__global__ void detect_mask_kernel(const unsigned int* __restrict__ mask,
                                   int* __restrict__ flag){
  __shared__ int cnt;
  const int t = threadIdx.x;
  if (t == 0) cnt = 0;
  __syncthreads();
  int local = 0;
  for (int i = t; i < 2048; i += 256){
    unsigned int v = mask[i];
    local += (v <= 1u) ? 1 : 0;
  }
  atomicAdd(&cnt, local);
  __syncthreads();
  if (t == 0){
    *flag = (cnt > 1843) ? 0 : ((cnt > 512) ? 2 : 1);
  }
}

// ---------- conv1: gather + 27x GEMM, h1 = sum_k mask*(x[nbr] @ W1[k]) ----------
__global__ __launch_bounds__(256)
void conv1_kernel(const float* __restrict__ x, const int* __restrict__ nbr,
                  const void* __restrict__ maskp, const float* __restrict__ W1,
                  const int* __restrict__ flagp, unsigned short* __restrict__ h1)
{
  __shared__ float xs[CIN][TILE_P + 2];   // transposed tile, pad 2: b64-aligned, conflict-free
  __shared__ float mf[TILE_P][KOFF];
  __shared__ int   ni[TILE_P][KOFF];

  const int t = threadIdx.x;
  const int pbase = blockIdx.x * TILE_P;
  const int flag = *flagp;

  for (int e = t; e < TILE_P * KOFF; e += 256){
    int r = e / KOFF, k = e - r * KOFF;
    int g = (pbase + r) * KOFF + k;
    ni[r][k] = nbr[g];
    float m;
    if (flag == 0)      m = (float)(((const int*)maskp)[g]);
    else if (flag == 1) m = (float)(((const unsigned char*)maskp)[g]);
    else                m = ((const float*)maskp)[g];
    mf[r][k] = m;
  }

  float acc[2][8];
  #pragma unroll
  for (int a = 0; a < 2; a++)
    #pragma unroll
    for (int j = 0; j < 8; j++) acc[a][j] = 0.f;

  const int pg = t >> 4;        // 0..15 -> points pg*2, pg*2+1
  const int cg = t & 15;        // 0..15 -> channels cg*8..cg*8+7
  const int c0 = cg * 8;
  const int srow = t >> 3;      // staging row 0..31
  const int sf0  = t & 7;       // staging float4 lane

  __syncthreads();

  for (int k = 0; k < KOFF; k++){
    // stage gathered, masked x row (transposed) into LDS; skip load if mask==0
    {
      const float m = mf[srow][k];
      const float4* src = reinterpret_cast<const float4*>(x + (size_t)ni[srow][k] * CIN);
      #pragma unroll
      for (int q = 0; q < 8; q++){
        const int f = sf0 + q * 8;
        float4 v;
        if (m != 0.f){
          v = src[f];
          v.x *= m; v.y *= m; v.z *= m; v.w *= m;
        } else {
          v = make_float4(0.f, 0.f, 0.f, 0.f);
        }
        const int i = f * 4;
        xs[i+0][srow] = v.x; xs[i+1][srow] = v.y;
        xs[i+2][srow] = v.z; xs[i+3][srow] = v.w;
      }
    }
    __syncthreads();

    const float* w1k = W1 + (size_t)k * (CIN * CMID) + c0;
    #pragma unroll 2
    for (int i = 0; i < CIN; i++){
      const float4 wa = *reinterpret_cast<const float4*>(w1k + i * CMID);
      const float4 wb = *reinterpret_cast<const float4*>(w1k + i * CMID + 4);
      const float2 xv = *reinterpret_cast<const float2*>(&xs[i][pg * 2]);
      const float w[8] = {wa.x, wa.y, wa.z, wa.w, wb.x, wb.y, wb.z, wb.w};
      #pragma unroll
      for (int j = 0; j < 8; j++){
        acc[0][j] = fmaf(xv.x, w[j], acc[0][j]);
        acc[1][j] = fmaf(xv.y, w[j], acc[1][j]);
      }
    }
    __syncthreads();
  }

  // write h1 (bf16), 2 points x 8 channels per thread, packed 16B stores
  #pragma unroll
  for (int a = 0; a < 2; a++){
    const int p = pbase + pg * 2 + a;
    unsigned short pk[8];
    #pragma unroll
    for (int j = 0; j < 8; j++) pk[j] = f2bf(acc[a][j]);
    uint4 u;
    u.x = (unsigned)pk[0] | ((unsigned)pk[1] << 16);
    u.y = (unsigned)pk[2] | ((unsigned)pk[3] << 16);
    u.z = (unsigned)pk[4] | ((unsigned)pk[5] << 16);
    u.w = (unsigned)pk[6] | ((unsigned)pk[7] << 16);
    *reinterpret_cast<uint4*>(h1 + (size_t)p * CMID + c0) = u;
  }
}

// ---------- BN stats (sum, sumsq per channel) ----------
__global__ void stats_bf16_kernel(const unsigned short* __restrict__ h,
                                  float* __restrict__ out)  // [2*CMID]
{
  const int t = threadIdx.x;
  const int c = t & 127;
  const int rsub = t >> 7;          // 0..1
  float s = 0.f, s2 = 0.f;
  for (size_t r = (size_t)blockIdx.x * 2 + rsub; r < NPTS; r += (size_t)gridDim.x * 2){
    float v = bf2f(h[r * CMID + c]);
    s += v; s2 += v * v;
  }
  __shared__ float red[256];
  red[t] = s; __syncthreads();
  if (t < 128) atomicAdd(&out[c], red[t] + red[t + 128]);
  __syncthreads();
  red[t] = s2; __syncthreads();
  if (t < 128) atomicAdd(&out[CMID + c], red[t] + red[t + 128]);
}

__global__ void stats_f32_kernel(const float* __restrict__ h,
                                 float* __restrict__ out)   // [2*CS]
{
  const int t = threadIdx.x;
  const int c = t & 31;
  const int rsub = t >> 5;          // 0..7
  float s = 0.f, s2 = 0.f;
  for (size_t r = (size_t)blockIdx.x * 8 + rsub; r < NPTS; r += (size_t)gridDim.x * 8){
    float v = h[r * CS + c];
    s += v; s2 += v * v;
  }
  __shared__ float red[256];
  red[t] = s; __syncthreads();
  if (t < 32){
    float tot = 0.f;
    #pragma unroll
    for (int u = 0; u < 8; u++) tot += red[u * 32 + t];
    atomicAdd(&out[c], tot);
  }
  __syncthreads();
  red[t] = s2; __syncthreads();
  if (t < 32){
    float tot = 0.f;
    #pragma unroll
    for (int u = 0; u < 8; u++) tot += red[u * 32 + t];
    atomicAdd(&out[CS + c], tot);
  }
}

// ---------- BN1 + ReLU + GEMM W2 (128->32) ----------
__global__ __launch_bounds__(256)
void bn1_gemm2_kernel(const unsigned short* __restrict__ h1, const float* __restrict__ stats1,
                      const float* __restrict__ gamma1, const float* __restrict__ beta1,
                      const float* __restrict__ W2, float* __restrict__ h2)
{
  __shared__ float w2s[CMID][CS];   // 16KB, [i][c]: conflict-free column reads
  __shared__ float hs[8][CMID];     // 4KB
  __shared__ float scl[CMID], sft[CMID];
  const int t = threadIdx.x;
  if (t < CMID){
    const float inv = 1.f / (float)NPTS;
    float mean = stats1[t] * inv;
    float var  = stats1[CMID + t] * inv - mean * mean;
    float rs = rsqrtf(var + BN_EPS);
    float sc = gamma1[t] * rs;
    scl[t] = sc; sft[t] = beta1[t] - mean * sc;
  }
  for (int e = t; e < CMID * CS / 4; e += 256)
    reinterpret_cast<float4*>(w2s)[e] = reinterpret_cast<const float4*>(W2)[e];
  __syncthreads();

  const int pblock = blockIdx.x * 32;
  const int pp = t >> 5, c = t & 31;

  for (int it = 0; it < 4; ++it){
    const int pb = pblock + it * 8;
    {
      const int col = c * 4;
      ushort4 v = *reinterpret_cast<const ushort4*>(h1 + (size_t)(pb + pp) * CMID + col);
      float f0 = fmaxf(bf2f(v.x) * scl[col+0] + sft[col+0], 0.f);
      float f1 = fmaxf(bf2f(v.y) * scl[col+1] + sft[col+1], 0.f);
      float f2 = fmaxf(bf2f(v.z) * scl[col+2] + sft[col+2], 0.f);
      float f3 = fmaxf(bf2f(v.w) * scl[col+3] + sft[col+3], 0.f);
      *reinterpret_cast<float4*>(&hs[pp][col]) = make_float4(f0, f1, f2, f3);
    }
    __syncthreads();
    float a = 0.f;
    #pragma unroll 4
    for (int i = 0; i < CMID; i++) a += hs[pp][i] * w2s[i][c];
    h2[(size_t)(pb + pp) * CS + c] = a;
    __syncthreads();
  }
}

// ---------- BN2 + GEMM W3 (32->8) ----------
__global__ __launch_bounds__(256)
void bn2_gemm3_kernel(const float* __restrict__ h2, const float* __restrict__ stats2,
                      const float* __restrict__ gamma2, const float* __restrict__ beta2,
                      const float* __restrict__ W3, float* __restrict__ out)
{
  __shared__ float w3s[CS][COUT];   // 1KB
  __shared__ float hs[32][36];      // pad 36: aligned float4 + conflict-free reads
  __shared__ float scl[CS], sft[CS];
  const int t = threadIdx.x;
  if (t < CS){
    const float inv = 1.f / (float)NPTS;
    float mean = stats2[t] * inv;
    float var  = stats2[CS + t] * inv - mean * mean;
    float rs = rsqrtf(var + BN_EPS);
    float sc = gamma2[t] * rs;
    scl[t] = sc; sft[t] = beta2[t] - mean * sc;
  }
  if (t < CS * COUT) w3s[t / COUT][t % COUT] = W3[t];
  __syncthreads();

  const int pblock = blockIdx.x * 32;
  const int r = t >> 3, c4 = (t & 7) * 4;
  {
    float4 v = *reinterpret_cast<const float4*>(h2 + (size_t)(pblock + r) * CS + c4);
    v.x = v.x * scl[c4+0] + sft[c4+0];
    v.y = v.y * scl[c4+1] + sft[c4+1];
    v.z = v.z * scl[c4+2] + sft[c4+2];
    v.w = v.w * scl[c4+3] + sft[c4+3];
    *reinterpret_cast<float4*>(&hs[r][c4]) = v;
  }
  __syncthreads();
  const int pp = t >> 3, c = t & 7;
  float a = 0.f;
  #pragma unroll
  for (int i = 0; i < CS; i++) a += hs[pp][i] * w3s[i][c];
  out[(size_t)(pblock + pp) * COUT + c] = a;
}

extern "C" void kernel_launch(void* const* d_in, const int* in_sizes, int n_in,
                              void* d_out, int out_size, void* d_ws, size_t ws_size,
                              hipStream_t stream) {
  const float* x    = (const float*)d_in[0];
  const int*   nbr  = (const int*)d_in[1];
  const void*  mask = d_in[2];
  const float* W1   = (const float*)d_in[3];
  const float* g1   = (const float*)d_in[4];
  const float* b1   = (const float*)d_in[5];
  const float* W2   = (const float*)d_in[6];
  const float* g2   = (const float*)d_in[7];
  const float* b2   = (const float*)d_in[8];
  const float* W3   = (const float*)d_in[9];
  float* out = (float*)d_out;

  char* ws = (char*)d_ws;
  int*   flag   = (int*)ws;
  float* stats1 = (float*)(ws + 256);          // 128 sum + 128 sumsq
  float* stats2 = (float*)(ws + 256 + 1024);   // 32 sum + 32 sumsq
  unsigned short* h1 = (unsigned short*)(ws + 4096);                    // [N][128] bf16
  float* h2 = (float*)(ws + 4096 + (size_t)NPTS * CMID * sizeof(unsigned short)); // [N][32] f32

  hipMemsetAsync(ws, 0, 4096, stream);
  detect_mask_kernel<<<1, 256, 0, stream>>>((const unsigned int*)mask, flag);
  conv1_kernel<<<NPTS / TILE_P, 256, 0, stream>>>(x, nbr, mask, W1, flag, h1);
  stats_bf16_kernel<<<512, 256, 0, stream>>>(h1, stats1);
  bn1_gemm2_kernel<<<NPTS / 32, 256, 0, stream>>>(h1, stats1, g1, b1, W2, h2);
  stats_f32_kernel<<<512, 256, 0, stream>>>(h2, stats2);
  bn2_gemm3_kernel<<<NPTS / 32, 256, 0, stream>>>(h2, stats2, g2, b2, W3, out);
}

// Round 3
// 2681.311 us; speedup vs baseline: 6.0889x; 6.0889x over previous
//
#include <hip/hip_runtime.h>
#include <hip/hip_bf16.h>

#define NPTS  300000
#define KOFF  27
#define CIN   256
#define CMID  128
#define CS    32
#define COUT  8
#define BN_EPS 1e-5f

typedef __bf16 bf16x8 __attribute__((ext_vector_type(8)));
typedef float  f32x4  __attribute__((ext_vector_type(4)));

// ---------- bf16 helpers (manual, RNE) ----------
__device__ __forceinline__ float bf2f(unsigned short u){
  return __uint_as_float(((unsigned int)u) << 16);
}
__device__ __forceinline__ float bf2f_lo(unsigned int w){
  return __uint_as_float(w << 16);
}
__device__ __forceinline__ float bf2f_hi(unsigned int w){
  return __uint_as_float(w & 0xffff0000u);
}
__device__ __forceinline__ unsigned short f2bf(float f){
  unsigned int x = __float_as_uint(f);
  return (unsigned short)((x + 0x7fffu + ((x >> 16) & 1u)) >> 16);
}

// ---------- mask dtype detection (unchanged, validated R2) ----------
__global__ void detect_mask_kernel(const unsigned int* __restrict__ mask,
                                   int* __restrict__ flag){
  __shared__ int cnt;
  const int t = threadIdx.x;
  if (t == 0) cnt = 0;
  __syncthreads();
  int local = 0;
  for (int i = t; i < 2048; i += 256){
    unsigned int v = mask[i];
    local += (v <= 1u) ? 1 : 0;
  }
  atomicAdd(&cnt, local);
  __syncthreads();
  if (t == 0) *flag = (cnt > 1843) ? 0 : ((cnt > 512) ? 2 : 1);
}

// ---------- x f32 -> bf16 (xb[N][256]) ----------
__global__ __launch_bounds__(256)
void cvt_x_kernel(const float* __restrict__ x, unsigned int* __restrict__ xb4){
  // process 8 floats -> 8 bf16 (one uint4 out) per iter
  const unsigned int total = NPTS * CIN / 8;   // 9,600,000
  for (unsigned int j = blockIdx.x * 256 + threadIdx.x; j < total; j += gridDim.x * 256){
    const float4* s = reinterpret_cast<const float4*>(x) + (size_t)j * 2;
    float4 a = s[0], b = s[1];
    uint4 o;
    o.x = (unsigned)f2bf(a.x) | ((unsigned)f2bf(a.y) << 16);
    o.y = (unsigned)f2bf(a.z) | ((unsigned)f2bf(a.w) << 16);
    o.z = (unsigned)f2bf(b.x) | ((unsigned)f2bf(b.y) << 16);
    o.w = (unsigned)f2bf(b.z) | ((unsigned)f2bf(b.w) << 16);
    reinterpret_cast<uint4*>(xb4)[j] = o;
  }
}

// ---------- W1 f32 [27][256][128] -> W1T bf16 [27][128][256] ----------
__global__ __launch_bounds__(256)
void cvt_w1t_kernel(const float* __restrict__ W1, unsigned short* __restrict__ w1t){
  __shared__ float ls[64][133];
  const int t = threadIdx.x;
  const int k = blockIdx.x >> 2, ib = blockIdx.x & 3;   // 27*4 blocks
  const float* src = W1 + (size_t)k * (CIN * CMID) + (size_t)ib * 64 * CMID;
  for (int e = t; e < 64 * 128; e += 256){
    int i = e >> 7, c = e & 127;
    ls[i][c] = src[e];
  }
  __syncthreads();
  unsigned short* dst = w1t + (size_t)k * (CMID * CIN) + ib * 64;
  for (int e = t; e < 64 * 128; e += 256){
    int i = e & 63, c = e >> 6;
    dst[(size_t)c * CIN + i] = f2bf(ls[i][c]);
  }
}

// ---------- conv1: gather + 27x bf16 MFMA GEMM -> h1T[128][NPTS] bf16 ----------
__global__ __launch_bounds__(256)
void conv1_mfma_kernel(const unsigned short* __restrict__ xb,
                       const int* __restrict__ nbr,
                       const void* __restrict__ maskp,
                       const unsigned short* __restrict__ W1T,
                       const int* __restrict__ flagp,
                       unsigned short* __restrict__ h1t)
{
  __shared__ __align__(16) char xs[64 * 512];   // 32KB swizzled bf16 A-tile [64][256]
  __shared__ int   ni[64][KOFF];
  __shared__ float mf[64][KOFF];

  const int t = threadIdx.x;
  const int pbase = blockIdx.x * 64;
  const int flag = *flagp;

  for (int e = t; e < 64 * KOFF; e += 256){
    int r = e / KOFF, k = e - r * KOFF;
    int p = pbase + r;
    float m = 0.f; int idx = 0;
    if (p < NPTS){
      int g = p * KOFF + k;
      idx = nbr[g];
      if (flag == 0)      m = (float)(((const int*)maskp)[g]);
      else if (flag == 1) m = (float)(((const unsigned char*)maskp)[g]);
      else                m = ((const float*)maskp)[g];
    }
    ni[r][k] = idx; mf[r][k] = m;
  }

  f32x4 acc[2][4];
  #pragma unroll
  for (int mm = 0; mm < 2; mm++)
    #pragma unroll
    for (int n = 0; n < 4; n++)
      acc[mm][n] = (f32x4){0.f, 0.f, 0.f, 0.f};

  const int lane = t & 63;
  const int wave = t >> 6;
  const int wr = wave >> 1;          // row half 0..1
  const int wc = wave & 1;           // col half 0..1
  const int l15 = lane & 15;
  const int l4  = lane >> 4;         // 0..3

  const int sr  = t >> 2;            // staging row 0..63
  const int sc0 = t & 3;             // staging chunk base

  __syncthreads();

  for (int k = 0; k < KOFF; ++k){
    // ---- stage gathered masked bf16 rows into swizzled LDS ----
    {
      const float m = mf[sr][k];
      const unsigned short* src = xb + (size_t)ni[sr][k] * CIN;
      #pragma unroll
      for (int q = 0; q < 8; ++q){
        const int c = sc0 + q * 4;                       // 16B chunk 0..31
        uint4 v = make_uint4(0u, 0u, 0u, 0u);
        if (m != 0.f) v = *reinterpret_cast<const uint4*>(src + c * 8);
        const int dst = sr * 512 + ((c * 16) ^ ((sr & 7) << 4));  // T2 XOR swizzle
        *reinterpret_cast<uint4*>(xs + dst) = v;
      }
    }
    __syncthreads();

    // ---- 8 K-steps of 16x16x32 MFMA ----
    const unsigned short* wk = W1T + (size_t)k * (CMID * CIN);
    #pragma unroll
    for (int kk = 0; kk < 8; ++kk){
      bf16x8 b[4];
      #pragma unroll
      for (int n = 0; n < 4; ++n){
        const int col = wc * 64 + n * 16 + l15;
        b[n] = *reinterpret_cast<const bf16x8*>(wk + (size_t)col * CIN + kk * 32 + l4 * 8);
      }
      #pragma unroll
      for (int mm = 0; mm < 2; ++mm){
        const int row = wr * 32 + mm * 16 + l15;
        const int off = row * 512 + ((kk * 64 + l4 * 16) ^ ((row & 7) << 4));
        bf16x8 a = *reinterpret_cast<const bf16x8*>(xs + off);
        #pragma unroll
        for (int n = 0; n < 4; ++n)
          acc[mm][n] = __builtin_amdgcn_mfma_f32_16x16x32_bf16(a, b[n], acc[mm][n], 0, 0, 0);
      }
    }
    __syncthreads();
  }

  // ---- epilogue: D row=(l>>4)*4+reg (point), col=l&15 (channel); store to h1T ----
  #pragma unroll
  for (int mm = 0; mm < 2; ++mm){
    const int row = pbase + wr * 32 + mm * 16 + l4 * 4;
    if (row + 3 < NPTS){
      #pragma unroll
      for (int n = 0; n < 4; ++n){
        const int col = wc * 64 + n * 16 + l15;
        ushort4 o;
        o.x = f2bf(acc[mm][n][0]);
        o.y = f2bf(acc[mm][n][1]);
        o.z = f2bf(acc[mm][n][2]);
        o.w = f2bf(acc[mm][n][3]);
        *reinterpret_cast<ushort4*>(h1t + (size_t)col * NPTS + row) = o;
      }
    }
  }
}

// ---------- stats over h1T: per-channel sum & sumsq (no atomics) ----------
__global__ __launch_bounds__(256)
void stats1_kernel(const unsigned short* __restrict__ h1t, float* __restrict__ stats1){
  const int c = blockIdx.x;                 // 0..127
  const int t = threadIdx.x;
  const uint4* p = reinterpret_cast<const uint4*>(h1t + (size_t)c * NPTS);
  float s = 0.f, s2 = 0.f;
  for (int i = t; i < NPTS / 8; i += 256){
    uint4 v = p[i];
    float f0 = bf2f_lo(v.x), f1 = bf2f_hi(v.x);
    float f2 = bf2f_lo(v.y), f3 = bf2f_hi(v.y);
    float f4 = bf2f_lo(v.z), f5 = bf2f_hi(v.z);
    float f6 = bf2f_lo(v.w), f7 = bf2f_hi(v.w);
    s  += ((f0 + f1) + (f2 + f3)) + ((f4 + f5) + (f6 + f7));
    s2 += ((f0*f0 + f1*f1) + (f2*f2 + f3*f3)) + ((f4*f4 + f5*f5) + (f6*f6 + f7*f7));
  }
  #pragma unroll
  for (int o = 32; o > 0; o >>= 1){
    s  += __shfl_xor(s, o);
    s2 += __shfl_xor(s2, o);
  }
  __shared__ float rs[4], rs2[4];
  const int wave = t >> 6;
  if ((t & 63) == 0){ rs[wave] = s; rs2[wave] = s2; }
  __syncthreads();
  if (t == 0){
    stats1[c]        = rs[0] + rs[1] + rs[2] + rs[3];
    stats1[CMID + c] = rs2[0] + rs2[1] + rs2[2] + rs2[3];
  }
}

// ---------- BN1 + ReLU + GEMM W2 (128->32), h1T input, h2[N][32] f32 out ----------
__global__ __launch_bounds__(256)
void bn1_gemm2_kernel(const unsigned short* __restrict__ h1t, const float* __restrict__ stats1,
                      const float* __restrict__ gamma1, const float* __restrict__ beta1,
                      const float* __restrict__ W2, float* __restrict__ h2)
{
  __shared__ float hs[64][129];    // [point][chan] BN+ReLU'd
  __shared__ float w2s[128][36];   // [i][c], padded for aligned float4 + banks
  __shared__ float scl[CMID], sft[CMID];
  const int t = threadIdx.x;
  const int pbase = blockIdx.x * 64;

  if (t < CMID){
    const float inv = 1.f / (float)NPTS;
    float mean = stats1[t] * inv;
    float var  = stats1[CMID + t] * inv - mean * mean;
    float rs = rsqrtf(var + BN_EPS);
    float sc = gamma1[t] * rs;
    scl[t] = sc; sft[t] = beta1[t] - mean * sc;
  }
  for (int e = t; e < CMID * CS; e += 256)
    w2s[e >> 5][e & 31] = W2[e];
  __syncthreads();

  {
    const int p = t & 63;
    const int gp = pbase + p;
    #pragma unroll
    for (int cc = 0; cc < 32; ++cc){
      const int c = (t >> 6) + cc * 4;
      float v = 0.f;
      if (gp < NPTS) v = bf2f(h1t[(size_t)c * NPTS + gp]);
      hs[p][c] = fmaxf(v * scl[c] + sft[c], 0.f);
    }
  }
  __syncthreads();

  const int cp = t >> 2;          // point 0..63
  const int c0 = (t & 3) * 8;     // 8 output cols
  float a0=0,a1=0,a2=0,a3=0,a4=0,a5=0,a6=0,a7=0;
  #pragma unroll 8
  for (int i = 0; i < CMID; ++i){
    const float hv = hs[cp][i];
    const float4 wa = *reinterpret_cast<const float4*>(&w2s[i][c0]);
    const float4 wb = *reinterpret_cast<const float4*>(&w2s[i][c0 + 4]);
    a0 = fmaf(hv, wa.x, a0); a1 = fmaf(hv, wa.y, a1);
    a2 = fmaf(hv, wa.z, a2); a3 = fmaf(hv, wa.w, a3);
    a4 = fmaf(hv, wb.x, a4); a5 = fmaf(hv, wb.y, a5);
    a6 = fmaf(hv, wb.z, a6); a7 = fmaf(hv, wb.w, a7);
  }
  if (pbase + cp < NPTS){
    float* o = h2 + (size_t)(pbase + cp) * CS + c0;
    *reinterpret_cast<float4*>(o)     = make_float4(a0, a1, a2, a3);
    *reinterpret_cast<float4*>(o + 4) = make_float4(a4, a5, a6, a7);
  }
}

// ---------- stats over h2 (row-major f32) ----------
__global__ void stats_f32_kernel(const float* __restrict__ h,
                                 float* __restrict__ out)   // [2*CS]
{
  const int t = threadIdx.x;
  const int c = t & 31;
  const int rsub = t >> 5;          // 0..7
  float s = 0.f, s2 = 0.f;
  for (size_t r = (size_t)blockIdx.x * 8 + rsub; r < NPTS; r += (size_t)gridDim.x * 8){
    float v = h[r * CS + c];
    s += v; s2 += v * v;
  }
  __shared__ float red[256];
  red[t] = s; __syncthreads();
  if (t < 32){
    float tot = 0.f;
    #pragma unroll
    for (int u = 0; u < 8; u++) tot += red[u * 32 + t];
    atomicAdd(&out[c], tot);
  }
  __syncthreads();
  red[t] = s2; __syncthreads();
  if (t < 32){
    float tot = 0.f;
    #pragma unroll
    for (int u = 0; u < 8; u++) tot += red[u * 32 + t];
    atomicAdd(&out[CS + c], tot);
  }
}

// ---------- BN2 + GEMM W3 (32->8) ----------
__global__ __launch_bounds__(256)
void bn2_gemm3_kernel(const float* __restrict__ h2, const float* __restrict__ stats2,
                      const float* __restrict__ gamma2, const float* __restrict__ beta2,
                      const float* __restrict__ W3, float* __restrict__ out)
{
  __shared__ float w3s[CS][COUT];   // 1KB
  __shared__ float hs[32][36];
  __shared__ float scl[CS], sft[CS];
  const int t = threadIdx.x;
  if (t < CS){
    const float inv = 1.f / (float)NPTS;
    float mean = stats2[t] * inv;
    float var  = stats2[CS + t] * inv - mean * mean;
    float rs = rsqrtf(var + BN_EPS);
    float sc = gamma2[t] * rs;
    scl[t] = sc; sft[t] = beta2[t] - mean * sc;
  }
  if (t < CS * COUT) w3s[t / COUT][t % COUT] = W3[t];
  __syncthreads();

  const int pblock = blockIdx.x * 32;
  const int r = t >> 3, c4 = (t & 7) * 4;
  {
    float4 v = *reinterpret_cast<const float4*>(h2 + (size_t)(pblock + r) * CS + c4);
    v.x = v.x * scl[c4+0] + sft[c4+0];
    v.y = v.y * scl[c4+1] + sft[c4+1];
    v.z = v.z * scl[c4+2] + sft[c4+2];
    v.w = v.w * scl[c4+3] + sft[c4+3];
    *reinterpret_cast<float4*>(&hs[r][c4]) = v;
  }
  __syncthreads();
  const int pp = t >> 3, c = t & 7;
  float a = 0.f;
  #pragma unroll
  for (int i = 0; i < CS; i++) a += hs[pp][i] * w3s[i][c];
  out[(size_t)(pblock + pp) * COUT + c] = a;
}

extern "C" void kernel_launch(void* const* d_in, const int* in_sizes, int n_in,
                              void* d_out, int out_size, void* d_ws, size_t ws_size,
                              hipStream_t stream) {
  const float* x    = (const float*)d_in[0];
  const int*   nbr  = (const int*)d_in[1];
  const void*  mask = d_in[2];
  const float* W1   = (const float*)d_in[3];
  const float* g1   = (const float*)d_in[4];
  const float* b1   = (const float*)d_in[5];
  const float* W2   = (const float*)d_in[6];
  const float* g2   = (const float*)d_in[7];
  const float* b2   = (const float*)d_in[8];
  const float* W3   = (const float*)d_in[9];
  float* out = (float*)d_out;

  char* ws = (char*)d_ws;
  int*   flag   = (int*)ws;                       // @0
  float* stats1 = (float*)(ws + 256);             // 256 f32 (1KB)
  float* stats2 = (float*)(ws + 1280);            // 64 f32
  unsigned short* h1t = (unsigned short*)(ws + 4096);                       // 76.8MB
  unsigned short* xb  = (unsigned short*)(ws + 4096 + 76800000ull);         // 153.6MB
  unsigned short* w1t = (unsigned short*)(ws + 4096 + 230400000ull);        // 1.77MB
  float*          h2  = (float*)(ws + 4096 + 232169472ull);                 // 38.4MB

  hipMemsetAsync(ws, 0, 4096, stream);
  detect_mask_kernel<<<1, 256, 0, stream>>>((const unsigned int*)mask, flag);
  cvt_x_kernel<<<2048, 256, 0, stream>>>(x, (unsigned int*)xb);
  cvt_w1t_kernel<<<KOFF * 4, 256, 0, stream>>>(W1, w1t);
  conv1_mfma_kernel<<<(NPTS + 63) / 64, 256, 0, stream>>>(xb, nbr, mask, w1t, flag, h1t);
  stats1_kernel<<<CMID, 256, 0, stream>>>(h1t, stats1);
  bn1_gemm2_kernel<<<(NPTS + 63) / 64, 256, 0, stream>>>(h1t, stats1, g1, b1, W2, h2);
  stats_f32_kernel<<<512, 256, 0, stream>>>(h2, stats2);
  bn2_gemm3_kernel<<<NPTS / 32, 256, 0, stream>>>(h2, stats2, g2, b2, W3, out);
}

// Round 4
// 2596.915 us; speedup vs baseline: 6.2868x; 1.0325x over previous
//
#include <hip/hip_runtime.h>
#include <hip/hip_bf16.h>

#define NPTS  300000
#define KOFF  27
#define CIN   256
#define CMID  128
#define CS    32
#define COUT  8
#define BN_EPS 1e-5f

typedef __bf16 bf16x8 __attribute__((ext_vector_type(8)));
typedef float  f32x4  __attribute__((ext_vector_type(4)));

// ---------- bf16 helpers (manual, RNE) ----------
__device__ __forceinline__ float bf2f(unsigned short u){
  return __uint_as_float(((unsigned int)u) << 16);
}
__device__ __forceinline__ float bf2f_lo(unsigned int w){
  return __uint_as_float(w << 16);
}
__device__ __forceinline__ float bf2f_hi(unsigned int w){
  return __uint_as_float(w & 0xffff0000u);
}
__device__ __forceinline__ unsigned short f2bf(float f){
  unsigned int x = __float_as_uint(f);
  return (unsigned short)((x + 0x7fffu + ((x >> 16) & 1u)) >> 16);
}

// async global->LDS, 16B per lane. LDS dest = wave-uniform base + lane*16.
__device__ __forceinline__ void gload_lds16(const void* g, void* l){
  __builtin_amdgcn_global_load_lds(
      (const __attribute__((address_space(1))) unsigned int*)g,
      (__attribute__((address_space(3))) unsigned int*)l, 16, 0, 0);
}

// ---------- mask dtype detection (validated R2) ----------
__global__ void detect_mask_kernel(const unsigned int* __restrict__ mask,
                                   int* __restrict__ flag){
  __shared__ int cnt;
  const int t = threadIdx.x;
  if (t == 0) cnt = 0;
  __syncthreads();
  int local = 0;
  for (int i = t; i < 2048; i += 256){
    unsigned int v = mask[i];
    local += (v <= 1u) ? 1 : 0;
  }
  atomicAdd(&cnt, local);
  __syncthreads();
  if (t == 0) *flag = (cnt > 1843) ? 0 : ((cnt > 512) ? 2 : 1);
}

// ---------- x f32 -> bf16 (xb[N][256]) ----------
__global__ __launch_bounds__(256)
void cvt_x_kernel(const float* __restrict__ x, unsigned int* __restrict__ xb4){
  const unsigned int total = NPTS * CIN / 8;
  for (unsigned int j = blockIdx.x * 256 + threadIdx.x; j < total; j += gridDim.x * 256){
    const float4* s = reinterpret_cast<const float4*>(x) + (size_t)j * 2;
    float4 a = s[0], b = s[1];
    uint4 o;
    o.x = (unsigned)f2bf(a.x) | ((unsigned)f2bf(a.y) << 16);
    o.y = (unsigned)f2bf(a.z) | ((unsigned)f2bf(a.w) << 16);
    o.z = (unsigned)f2bf(b.x) | ((unsigned)f2bf(b.y) << 16);
    o.w = (unsigned)f2bf(b.z) | ((unsigned)f2bf(b.w) << 16);
    reinterpret_cast<uint4*>(xb4)[j] = o;
  }
}

// ---------- W1 f32 [27][256][128] -> W1T bf16 [27][128][256] ----------
__global__ __launch_bounds__(256)
void cvt_w1t_kernel(const float* __restrict__ W1, unsigned short* __restrict__ w1t){
  __shared__ float ls[64][133];
  const int t = threadIdx.x;
  const int k = blockIdx.x >> 2, ib = blockIdx.x & 3;
  const float* src = W1 + (size_t)k * (CIN * CMID) + (size_t)ib * 64 * CMID;
  for (int e = t; e < 64 * 128; e += 256){
    int i = e >> 7, c = e & 127;
    ls[i][c] = src[e];
  }
  __syncthreads();
  unsigned short* dst = w1t + (size_t)k * (CMID * CIN) + ib * 64;
  for (int e = t; e < 64 * 128; e += 256){
    int i = e & 63, c = e >> 6;
    dst[(size_t)c * CIN + i] = f2bf(ls[i][c]);
  }
}

// ---------- conv1 staging: one wave stages its 16 rows of the A tile ----------
// Linear LDS dest; XOR swizzle realized by permuting the per-lane GLOBAL source
// chunk (rule: both-sides-or-neither). Masked rows read a zero page.
__device__ __forceinline__ void stage_tile(char* xsbuf, const int (*ni)[KOFF],
                                           const unsigned short* __restrict__ xb,
                                           const unsigned short* __restrict__ zp,
                                           int wave, int lane, int k)
{
  const int half  = lane >> 5;        // 0/1: which of the 2 rows this instr covers
  const int cphys = lane & 31;        // 16B chunk position in linear LDS row
  #pragma unroll
  for (int i = 0; i < 8; ++i){
    const int r0 = wave * 16 + i * 2;
    const int r  = r0 + half;
    const int idxv = ni[r][k];
    const int clog = cphys ^ (r & 7); // pre-swizzled source chunk
    const unsigned short* src = (idxv < 0) ? (zp + clog * 8)
                                           : (xb + (size_t)idxv * CIN + clog * 8);
    gload_lds16(src, xsbuf + r0 * 512);
  }
}

// ---------- conv1: gather + 27x bf16 MFMA GEMM -> h1T[128][NPTS] bf16 ----------
__global__ __launch_bounds__(256, 2)
void conv1_mfma_kernel(const unsigned short* __restrict__ xb,
                       const int* __restrict__ nbr,
                       const void* __restrict__ maskp,
                       const unsigned short* __restrict__ W1T,
                       const int* __restrict__ flagp,
                       const unsigned short* __restrict__ zp,
                       unsigned short* __restrict__ h1t)
{
  __shared__ __align__(16) char xs[2][64 * 512];  // 2x32KB double-buffered A tile
  __shared__ int ni[64][KOFF];                    // masked idx: -1 => zero row

  const int t = threadIdx.x;
  const int pbase = blockIdx.x * 64;
  const int flag = *flagp;

  for (int e = t; e < 64 * KOFF; e += 256){
    int r = e / KOFF, k = e - r * KOFF;
    int p = pbase + r;
    int v = -1;
    if (p < NPTS){
      int g = p * KOFF + k;
      float m;
      if (flag == 0)      m = (float)(((const int*)maskp)[g]);
      else if (flag == 1) m = (float)(((const unsigned char*)maskp)[g]);
      else                m = ((const float*)maskp)[g];
      if (m != 0.f) v = nbr[g];
    }
    ni[r][k] = v;
  }

  const int lane = t & 63;
  const int wave = t >> 6;
  const int wr = wave >> 1;
  const int wc = wave & 1;
  const int l15 = lane & 15;
  const int l4  = lane >> 4;

  f32x4 acc[2][4];
  #pragma unroll
  for (int mm = 0; mm < 2; mm++)
    #pragma unroll
    for (int n = 0; n < 4; n++)
      acc[mm][n] = (f32x4){0.f, 0.f, 0.f, 0.f};

  __syncthreads();                       // ni visible
  stage_tile(xs[0], ni, xb, zp, wave, lane, 0);
  __syncthreads();                       // drains vmcnt(0): buf0 ready

  for (int k = 0; k < KOFF; ++k){
    const int cur = k & 1;

    // 1) B-tile for k into registers (issued FIRST so MFMA waits leave the
    //    prefetch below in flight: vmcnt FIFO)
    bf16x8 breg[8][4];
    const unsigned short* wk = W1T + (size_t)k * (CMID * CIN);
    #pragma unroll
    for (int kk = 0; kk < 8; ++kk)
      #pragma unroll
      for (int n = 0; n < 4; ++n){
        const int col = wc * 64 + n * 16 + l15;
        breg[kk][n] = *reinterpret_cast<const bf16x8*>(wk + (size_t)col * CIN + kk * 32 + l4 * 8);
      }

    // 2) prefetch A tile for k+1 into the other buffer (overlaps MFMA below)
    if (k + 1 < KOFF) stage_tile(xs[cur ^ 1], ni, xb, zp, wave, lane, k + 1);

    // 3) MFMA on current buffer
    #pragma unroll
    for (int kk = 0; kk < 8; ++kk){
      #pragma unroll
      for (int mm = 0; mm < 2; ++mm){
        const int row = wr * 32 + mm * 16 + l15;
        const int off = row * 512 + ((kk * 64 + l4 * 16) ^ ((row & 7) << 4));
        bf16x8 a = *reinterpret_cast<const bf16x8*>(xs[cur] + off);
        #pragma unroll
        for (int n = 0; n < 4; ++n)
          acc[mm][n] = __builtin_amdgcn_mfma_f32_16x16x32_bf16(a, breg[kk][n], acc[mm][n], 0, 0, 0);
      }
    }

    // 4) one barrier per iter: syncthreads' vmcnt(0) drain waits only on the
    //    prefetch, which had the whole MFMA phase to complete
    __syncthreads();
  }

  // epilogue: D col=lane&15 (channel), row=(lane>>4)*4+reg (point) -> h1T
  #pragma unroll
  for (int mm = 0; mm < 2; ++mm){
    const int row = pbase + wr * 32 + mm * 16 + l4 * 4;
    if (row + 3 < NPTS){
      #pragma unroll
      for (int n = 0; n < 4; ++n){
        const int col = wc * 64 + n * 16 + l15;
        ushort4 o;
        o.x = f2bf(acc[mm][n][0]);
        o.y = f2bf(acc[mm][n][1]);
        o.z = f2bf(acc[mm][n][2]);
        o.w = f2bf(acc[mm][n][3]);
        *reinterpret_cast<ushort4*>(h1t + (size_t)col * NPTS + row) = o;
      }
    }
  }
}

// ---------- stats over h1T: per-channel sum & sumsq ----------
__global__ __launch_bounds__(256)
void stats1_kernel(const unsigned short* __restrict__ h1t, float* __restrict__ stats1){
  const int c = blockIdx.x;
  const int t = threadIdx.x;
  const uint4* p = reinterpret_cast<const uint4*>(h1t + (size_t)c * NPTS);
  float s = 0.f, s2 = 0.f;
  for (int i = t; i < NPTS / 8; i += 256){
    uint4 v = p[i];
    float f0 = bf2f_lo(v.x), f1 = bf2f_hi(v.x);
    float f2 = bf2f_lo(v.y), f3 = bf2f_hi(v.y);
    float f4 = bf2f_lo(v.z), f5 = bf2f_hi(v.z);
    float f6 = bf2f_lo(v.w), f7 = bf2f_hi(v.w);
    s  += ((f0 + f1) + (f2 + f3)) + ((f4 + f5) + (f6 + f7));
    s2 += ((f0*f0 + f1*f1) + (f2*f2 + f3*f3)) + ((f4*f4 + f5*f5) + (f6*f6 + f7*f7));
  }
  #pragma unroll
  for (int o = 32; o > 0; o >>= 1){
    s  += __shfl_xor(s, o);
    s2 += __shfl_xor(s2, o);
  }
  __shared__ float rs[4], rs2[4];
  const int wave = t >> 6;
  if ((t & 63) == 0){ rs[wave] = s; rs2[wave] = s2; }
  __syncthreads();
  if (t == 0){
    stats1[c]        = rs[0] + rs[1] + rs[2] + rs[3];
    stats1[CMID + c] = rs2[0] + rs2[1] + rs2[2] + rs2[3];
  }
}

// ---------- BN1 + ReLU + GEMM W2 (128->32), h1T input, h2[N][32] f32 out ----------
__global__ __launch_bounds__(256)
void bn1_gemm2_kernel(const unsigned short* __restrict__ h1t, const float* __restrict__ stats1,
                      const float* __restrict__ gamma1, const float* __restrict__ beta1,
                      const float* __restrict__ W2, float* __restrict__ h2)
{
  __shared__ float hs[64][129];
  __shared__ float w2s[128][36];
  __shared__ float scl[CMID], sft[CMID];
  const int t = threadIdx.x;
  const int pbase = blockIdx.x * 64;

  if (t < CMID){
    const float inv = 1.f / (float)NPTS;
    float mean = stats1[t] * inv;
    float var  = stats1[CMID + t] * inv - mean * mean;
    float rs = rsqrtf(var + BN_EPS);
    float sc = gamma1[t] * rs;
    scl[t] = sc; sft[t] = beta1[t] - mean * sc;
  }
  for (int e = t; e < CMID * CS; e += 256)
    w2s[e >> 5][e & 31] = W2[e];
  __syncthreads();

  {
    const int tp = t & 31;       // point pair index
    const int cg = t >> 5;       // 0..7
    const int p0 = 2 * tp;
    #pragma unroll
    for (int cc = 0; cc < 16; ++cc){
      const int c = cg + cc * 8;
      unsigned int v = 0;
      if (pbase + p0 < NPTS)     // NPTS even: pairs never straddle
        v = *reinterpret_cast<const unsigned int*>(h1t + (size_t)c * NPTS + pbase + p0);
      float flo = bf2f_lo(v), fhi = bf2f_hi(v);
      hs[p0][c]     = fmaxf(flo * scl[c] + sft[c], 0.f);
      hs[p0 + 1][c] = fmaxf(fhi * scl[c] + sft[c], 0.f);
    }
  }
  __syncthreads();

  const int cp = t >> 2;
  const int c0 = (t & 3) * 8;
  float a0=0,a1=0,a2=0,a3=0,a4=0,a5=0,a6=0,a7=0;
  #pragma unroll 8
  for (int i = 0; i < CMID; ++i){
    const float hv = hs[cp][i];
    const float4 wa = *reinterpret_cast<const float4*>(&w2s[i][c0]);
    const float4 wb = *reinterpret_cast<const float4*>(&w2s[i][c0 + 4]);
    a0 = fmaf(hv, wa.x, a0); a1 = fmaf(hv, wa.y, a1);
    a2 = fmaf(hv, wa.z, a2); a3 = fmaf(hv, wa.w, a3);
    a4 = fmaf(hv, wb.x, a4); a5 = fmaf(hv, wb.y, a5);
    a6 = fmaf(hv, wb.z, a6); a7 = fmaf(hv, wb.w, a7);
  }
  if (pbase + cp < NPTS){
    float* o = h2 + (size_t)(pbase + cp) * CS + c0;
    *reinterpret_cast<float4*>(o)     = make_float4(a0, a1, a2, a3);
    *reinterpret_cast<float4*>(o + 4) = make_float4(a4, a5, a6, a7);
  }
}

// ---------- stats over h2 (row-major f32) ----------
__global__ void stats_f32_kernel(const float* __restrict__ h,
                                 float* __restrict__ out)
{
  const int t = threadIdx.x;
  const int c = t & 31;
  const int rsub = t >> 5;
  float s = 0.f, s2 = 0.f;
  for (size_t r = (size_t)blockIdx.x * 8 + rsub; r < NPTS; r += (size_t)gridDim.x * 8){
    float v = h[r * CS + c];
    s += v; s2 += v * v;
  }
  __shared__ float red[256];
  red[t] = s; __syncthreads();
  if (t < 32){
    float tot = 0.f;
    #pragma unroll
    for (int u = 0; u < 8; u++) tot += red[u * 32 + t];
    atomicAdd(&out[c], tot);
  }
  __syncthreads();
  red[t] = s2; __syncthreads();
  if (t < 32){
    float tot = 0.f;
    #pragma unroll
    for (int u = 0; u < 8; u++) tot += red[u * 32 + t];
    atomicAdd(&out[CS + c], tot);
  }
}

// ---------- BN2 + GEMM W3 (32->8) ----------
__global__ __launch_bounds__(256)
void bn2_gemm3_kernel(const float* __restrict__ h2, const float* __restrict__ stats2,
                      const float* __restrict__ gamma2, const float* __restrict__ beta2,
                      const float* __restrict__ W3, float* __restrict__ out)
{
  __shared__ float w3s[CS][COUT];
  __shared__ float hs[32][36];
  __shared__ float scl[CS], sft[CS];
  const int t = threadIdx.x;
  if (t < CS){
    const float inv = 1.f / (float)NPTS;
    float mean = stats2[t] * inv;
    float var  = stats2[CS + t] * inv - mean * mean;
    float rs = rsqrtf(var + BN_EPS);
    float sc = gamma2[t] * rs;
    scl[t] = sc; sft[t] = beta2[t] - mean * sc;
  }
  if (t < CS * COUT) w3s[t / COUT][t % COUT] = W3[t];
  __syncthreads();

  const int pblock = blockIdx.x * 32;
  const int r = t >> 3, c4 = (t & 7) * 4;
  {
    float4 v = *reinterpret_cast<const float4*>(h2 + (size_t)(pblock + r) * CS + c4);
    v.x = v.x * scl[c4+0] + sft[c4+0];
    v.y = v.y * scl[c4+1] + sft[c4+1];
    v.z = v.z * scl[c4+2] + sft[c4+2];
    v.w = v.w * scl[c4+3] + sft[c4+3];
    *reinterpret_cast<float4*>(&hs[r][c4]) = v;
  }
  __syncthreads();
  const int pp = t >> 3, c = t & 7;
  float a = 0.f;
  #pragma unroll
  for (int i = 0; i < CS; i++) a += hs[pp][i] * w3s[i][c];
  out[(size_t)(pblock + pp) * COUT + c] = a;
}

extern "C" void kernel_launch(void* const* d_in, const int* in_sizes, int n_in,
                              void* d_out, int out_size, void* d_ws, size_t ws_size,
                              hipStream_t stream) {
  const float* x    = (const float*)d_in[0];
  const int*   nbr  = (const int*)d_in[1];
  const void*  mask = d_in[2];
  const float* W1   = (const float*)d_in[3];
  const float* g1   = (const float*)d_in[4];
  const float* b1   = (const float*)d_in[5];
  const float* W2   = (const float*)d_in[6];
  const float* g2   = (const float*)d_in[7];
  const float* b2   = (const float*)d_in[8];
  const float* W3   = (const float*)d_in[9];
  float* out = (float*)d_out;

  char* ws = (char*)d_ws;
  int*   flag   = (int*)ws;                        // @0
  unsigned short* zp = (unsigned short*)(ws + 1024);  // 512B zero page
  float* stats1 = (float*)(ws + 2048);             // 256 f32
  float* stats2 = (float*)(ws + 3072);             // 64 f32
  unsigned short* h1t = (unsigned short*)(ws + 4096);                       // 76.8MB
  unsigned short* xb  = (unsigned short*)(ws + 4096 + 76800000ull);         // 153.6MB
  unsigned short* w1t = (unsigned short*)(ws + 4096 + 230400000ull);        // 1.77MB
  float*          h2  = (float*)(ws + 4096 + 232169472ull);                 // 38.4MB

  hipMemsetAsync(ws, 0, 4096, stream);
  detect_mask_kernel<<<1, 256, 0, stream>>>((const unsigned int*)mask, flag);
  cvt_x_kernel<<<2048, 256, 0, stream>>>(x, (unsigned int*)xb);
  cvt_w1t_kernel<<<KOFF * 4, 256, 0, stream>>>(W1, w1t);
  conv1_mfma_kernel<<<(NPTS + 63) / 64, 256, 0, stream>>>(xb, nbr, mask, w1t, flag, zp, h1t);
  stats1_kernel<<<CMID, 256, 0, stream>>>(h1t, stats1);
  bn1_gemm2_kernel<<<(NPTS + 63) / 64, 256, 0, stream>>>(h1t, stats1, g1, b1, W2, h2);
  stats_f32_kernel<<<512, 256, 0, stream>>>(h2, stats2);
  bn2_gemm3_kernel<<<NPTS / 32, 256, 0, stream>>>(h2, stats2, g2, b2, W3, out);
}